// Round 6
// baseline (133.658 us; speedup 1.0000x reference)
//
#include <hip/hip_runtime.h>

// Involution b=8, c=64, h=w=128, K=3, G=8, r=2.
// kern = Wc @ x_center + bb, Wc = w_span@w_reduce (72x64), bb = w_span@b_reduce + b_span.
// R13 = R11 math (2 px/thread, octant split, 2048 blocks, XCD swizzle,
//   bitwise-identical accumulation order) + SCHED_BARRIER(0)-PINNED PIPELINE.
//   R12 post-mortem: VGPR stayed 36 -> compiler SANK all batched loads back
//   (pressure-minimizing scheduler); MLP was never applied. sched_barrier(0)
//   fences region membership: loads before the fence cannot sink past it.
//   - Phase A: 8-ch clusters, depth-3 buffers; each region = 144 FMA + next
//     cluster's loads; a load issues ~3 regions (~860cy) before its use.
//   - Phase B: taps ch0..5 issued inside last 3 PhA regions (addresses depend
//     only on h,w0, hoisted pre-PhA); ch6..7 after ch0..1 retire (VGPR cap).
//   Treatment check: VGPR must rise to ~95-126. Spill check: WRITE==32768KB.

#define HW 16384   // 128*128
#define WPX 128
#define SB() __builtin_amdgcn_sched_barrier(0)

// ws layout: [0,72) bb ;  [72 + o*576 + c*9 + j) Wg[o][c][j]   (o=group 0..7)
__global__ void invol_setup(const float* __restrict__ w_reduce,
                            const float* __restrict__ b_reduce,
                            const float* __restrict__ w_span,
                            const float* __restrict__ b_span,
                            float* __restrict__ ws)
{
    const int tid = blockIdx.x * 256 + threadIdx.x;   // 0..4607
    if (tid >= 72 * 64) return;
    const int row = tid >> 6;     // 0..71  (= g*9 + j)
    const int c   = tid & 63;
    float s = 0.f;
#pragma unroll
    for (int i = 0; i < 32; ++i)
        s = fmaf(w_span[row * 32 + i], w_reduce[i * 64 + c], s);
    ws[72 + (row / 9) * 576 + c * 9 + (row % 9)] = s;
    if (c == 0) {
        float t = b_span[row];
#pragma unroll
        for (int i = 0; i < 32; ++i)
            t = fmaf(w_span[row * 32 + i], b_reduce[i], t);
        ws[row] = t;
    }
}

// load 8 float2 (channels C0..C0+7) into BUF
#define LDA(BUF, C0)                                                          \
    _Pragma("unroll")                                                         \
    for (int i = 0; i < 8; ++i)                                               \
        BUF[i] = *reinterpret_cast<const float2*>(xb + (size_t)((C0) + i) * HW);

// 8 channels x 9 outputs x 2 pixels of FMA (ascending c => R11 accum order)
#define FMAA(BUF, C0)                                                         \
    _Pragma("unroll")                                                         \
    for (int i = 0; i < 8; ++i) {                                             \
        _Pragma("unroll")                                                     \
        for (int j = 0; j < 9; ++j) {                                         \
            const float wv = Wg[((C0) + i) * 9 + j];                          \
            kg[j].x = fmaf(wv, BUF[i].x, kg[j].x);                            \
            kg[j].y = fmaf(wv, BUF[i].y, kg[j].y);                            \
        }                                                                     \
    }

// issue the 9 tap loads for local channel CI
#define LDB(CI)                                                               \
    {                                                                         \
        const float* xc = xb + (size_t)(o * 8 + (CI)) * HW;                   \
        _Pragma("unroll")                                                     \
        for (int t = 0; t < 3; ++t) {                                         \
            vC[(CI) * 3 + t] = *reinterpret_cast<const float2*>(xc + rof[t]); \
            vL[(CI) * 3 + t] = xc[rof[t] + dwl];                              \
            vR[(CI) * 3 + t] = xc[rof[t] + dwr];                              \
        }                                                                     \
    }

// consume channel CI: 18 FMA + float2 store (R11-identical)
#define FMAB(CI)                                                              \
    {                                                                         \
        float acc0 = 0.f, acc1 = 0.f;                                         \
        _Pragma("unroll")                                                     \
        for (int t = 0; t < 3; ++t) {                                         \
            acc0 = fmaf(kg[t * 3 + 0].x, vL[(CI) * 3 + t],   acc0);           \
            acc0 = fmaf(kg[t * 3 + 1].x, vC[(CI) * 3 + t].x, acc0);           \
            acc0 = fmaf(kg[t * 3 + 2].x, vC[(CI) * 3 + t].y, acc0);           \
            acc1 = fmaf(kg[t * 3 + 0].y, vC[(CI) * 3 + t].x, acc1);           \
            acc1 = fmaf(kg[t * 3 + 1].y, vC[(CI) * 3 + t].y, acc1);           \
            acc1 = fmaf(kg[t * 3 + 2].y, vR[(CI) * 3 + t],   acc1);           \
        }                                                                     \
        *reinterpret_cast<float2*>(out + imgoff + (size_t)(o * 8 + (CI)) * HW \
                                   + hw0) = make_float2(acc0, acc1);          \
    }

__global__ __launch_bounds__(256, 4) void invol_main(
    const float* __restrict__ x,
    const float* __restrict__ ws,
    float* __restrict__ out)
{
    // XCD-aware swizzle: nwg = 2048, 8 XCDs, 256 logical ids per XCD.
    const int bid     = blockIdx.x;
    const int logical = (bid & 7) * 256 + (bid >> 3);
    const int o  = logical & 7;             // octant / group — SCALAR (SGPR)
    const int pb = logical >> 3;            // pair-block (256 pixel-pairs)

    const int P2  = pb * 256 + threadIdx.x; // pixel-pair id, 0..65535
    const int b   = P2 >> 13;               // 8192 pairs per image
    const int hw0 = (P2 & 8191) << 1;       // even pixel index
    const int h   = hw0 >> 7;
    const int w0  = hw0 & 127;              // even, 0..126

    const size_t imgoff = (size_t)b * 64 * HW;
    const float* xb  = x + imgoff + hw0;
    const float* Wg  = ws + 72 + o * 576;   // [c][9], scalar base
    const float* bbg = ws + o * 9;          // group bias, 9 floats

    // ---- Phase B address math hoisted (depends only on h, w0) ----
    int   rof[3];
    float rmask[3];
#pragma unroll
    for (int t = 0; t < 3; ++t) {
        const int hh = h + t - 1;
        const int hc = hh < 0 ? 0 : (hh > 127 ? 127 : hh);
        rof[t]   = (hc - h) * WPX;
        rmask[t] = ((unsigned)hh < 128u) ? 1.f : 0.f;
    }
    const int dwl = (w0 == 0)   ? 0 : -1;   // left edge load col (clamped)
    const int dwr = (w0 == 126) ? 1 : 2;    // right edge load col (clamped)

    // ---- phase A: 8 clusters of 8 ch, depth-3 pipeline, SB-pinned ----
    float2 kg[9];
#pragma unroll
    for (int j = 0; j < 9; ++j) { const float t = bbg[j]; kg[j] = make_float2(t, t); }

    float2 xva[8], xvb[8], xvc[8];
    float2 vC[24];
    float  vL[24], vR[24];

    LDA(xva, 0)
    LDA(xvb, 8)
    LDA(xvc, 16)
    SB();
    FMAA(xva, 0)  LDA(xva, 24)
    SB();
    FMAA(xvb, 8)  LDA(xvb, 32)
    SB();
    FMAA(xvc, 16) LDA(xvc, 40)
    SB();
    FMAA(xva, 24) LDA(xva, 48)
    SB();
    FMAA(xvb, 32) LDA(xvb, 56)
    SB();
    FMAA(xvc, 40) LDB(0) LDB(1)
    SB();
    FMAA(xva, 48) LDB(2) LDB(3)
    SB();
    FMAA(xvb, 56) LDB(4) LDB(5)
    SB();

    // ---- masks folded into taps (after PhA, before PhB consumption) ----
#pragma unroll
    for (int t = 0; t < 3; ++t) {
#pragma unroll
        for (int d = 0; d < 3; ++d) {
            kg[t * 3 + d].x *= rmask[t];
            kg[t * 3 + d].y *= rmask[t];
        }
    }
    if (w0 == 0)   { kg[0].x = 0.f; kg[3].x = 0.f; kg[6].x = 0.f; }
    if (w0 == 126) { kg[2].y = 0.f; kg[5].y = 0.f; kg[8].y = 0.f; }

    // ---- phase B: consume ch0..1, then issue ch6..7 (VGPR cap), rest free ----
    FMAB(0)
    FMAB(1)
    LDB(6) LDB(7)
    SB();
    FMAB(2)
    FMAB(3)
    FMAB(4)
    FMAB(5)
    FMAB(6)
    FMAB(7)
}

// fallback (round-1 kernel) if ws is too small for the weight scratch
__global__ __launch_bounds__(256) void invol_fused_fallback(
    const float* __restrict__ x,
    const float* __restrict__ w_reduce,
    const float* __restrict__ b_reduce,
    const float* __restrict__ w_span,
    const float* __restrict__ b_span,
    float* __restrict__ out)
{
    const int pid = blockIdx.x * 256 + threadIdx.x;
    const int b  = pid >> 14;
    const int hw = pid & 16383;
    const int h  = hw >> 7;
    const int w  = hw & 127;
    const float* xb   = x   + (size_t)b * 64 * HW + hw;
    float*       outb = out + (size_t)b * 64 * HW + hw;
    float y[32];
#pragma unroll
    for (int o = 0; o < 32; ++o) y[o] = b_reduce[o];
#pragma unroll 4
    for (int c = 0; c < 64; ++c) {
        const float xc = xb[(size_t)c * HW];
#pragma unroll
        for (int o = 0; o < 32; ++o)
            y[o] = fmaf(w_reduce[o * 64 + c], xc, y[o]);
    }
    for (int g = 0; g < 8; ++g) {
        float kg[9];
#pragma unroll
        for (int k = 0; k < 9; ++k) {
            float s = b_span[g * 9 + k];
#pragma unroll
            for (int i = 0; i < 32; ++i)
                s = fmaf(w_span[(g * 9 + k) * 32 + i], y[i], s);
            kg[k] = s;
        }
#pragma unroll
        for (int ci = 0; ci < 8; ++ci) {
            const int c = g * 8 + ci;
            const float* xc = xb + (size_t)c * HW;
            float acc = 0.f;
#pragma unroll
            for (int k = 0; k < 9; ++k) {
                const int dh = k / 3 - 1, dw = k % 3 - 1;
                const int hh = h + dh, ww = w + dw;
                float v = ((unsigned)hh < 128u && (unsigned)ww < 128u)
                          ? xc[dh * WPX + dw] : 0.f;
                acc = fmaf(kg[k], v, acc);
            }
            outb[(size_t)c * HW] = acc;
        }
    }
}

extern "C" void kernel_launch(void* const* d_in, const int* in_sizes, int n_in,
                              void* d_out, int out_size, void* d_ws, size_t ws_size,
                              hipStream_t stream) {
    const float* x        = (const float*)d_in[0];
    const float* w_reduce = (const float*)d_in[1];
    const float* b_reduce = (const float*)d_in[2];
    const float* w_span   = (const float*)d_in[3];
    const float* b_span   = (const float*)d_in[4];
    float* out = (float*)d_out;

    const size_t ws_needed = (size_t)(72 + 8 * 64 * 9) * sizeof(float);  // 18720 B
    if (ws_size >= ws_needed) {
        float* ws = (float*)d_ws;
        invol_setup<<<18, 256, 0, stream>>>(w_reduce, b_reduce, w_span, b_span, ws);
        const int npairs = 8 * 128 * 128 / 2;          // 65536
        invol_main<<<npairs / 256 * 8, 256, 0, stream>>>(x, ws, out);  // 2048 blocks
    } else {
        const int npix = 8 * 128 * 128;
        invol_fused_fallback<<<npix / 256, 256, 0, stream>>>(
            x, w_reduce, b_reduce, w_span, b_span, out);
    }
}

// Round 7
// 74.626 us; speedup vs baseline: 1.7910x; 1.7910x over previous
//
#include <hip/hip_runtime.h>

// Involution b=8, c=64, h=w=128, K=3, G=8, r=2.
// kern = Wc @ x_center + bb, Wc = w_span@w_reduce (72x64), bb = w_span@b_reduce + b_span.
// R14: BYTE-REDUCTION round. Ledger R7-R13 fits "wall ~ bytes through per-CU
//   load pipes at ~16 B/cy" — every prior round moved bytes between pipes,
//   none reduced them. This round: 2 px/thread + HALF split (4 groups = 32
//   output channels per block; kg = 36 float2 = 72 VGPR).
//   bytes/px: PhA 64 f2 x 2 splits = 512 (was 1024-2048), PhB 48 B/ch-pair
//   x 64 = 1536 (was 2304), store 256 -> 2304 B/px = 0.64x R7.
//   - PhA loop DYNAMIC (unroll 1): code ~5KB, kg statically indexed (no
//     scratch); PhB fully unrolled (static kg group index).
//   - 512 blocks, bijective XCD swizzle: 64 logical/XCD -> image k on XCD k.
//   - NO sched_barrier (R13: spill), NO inline asm (R9: sched damage).

#define HW 16384   // 128*128
#define WPX 128

// ws layout: [0,72) bb (g-major: g*9+j) ;
//            [72 + half*2304 + c*36 + o') Wh[half][c][o'], o' = (g%4)*9 + j
__global__ void invol_setup(const float* __restrict__ w_reduce,
                            const float* __restrict__ b_reduce,
                            const float* __restrict__ w_span,
                            const float* __restrict__ b_span,
                            float* __restrict__ ws)
{
    const int tid = blockIdx.x * 256 + threadIdx.x;   // 0..4607
    if (tid >= 72 * 64) return;
    const int row = tid >> 6;     // 0..71  (= g*9 + j)
    const int c   = tid & 63;
    float s = 0.f;
#pragma unroll
    for (int i = 0; i < 32; ++i)
        s = fmaf(w_span[row * 32 + i], w_reduce[i * 64 + c], s);
    ws[72 + (row / 36) * 2304 + c * 36 + (row % 36)] = s;
    if (c == 0) {
        float t = b_span[row];
#pragma unroll
        for (int i = 0; i < 32; ++i)
            t = fmaf(w_span[row * 32 + i], b_reduce[i], t);
        ws[row] = t;
    }
}

__global__ __launch_bounds__(256, 4) void invol_main(
    const float* __restrict__ x,
    const float* __restrict__ ws,
    float* __restrict__ out)
{
    // XCD-aware bijective swizzle: nwg = 512, 8 XCDs, 64 logical ids per XCD.
    const int bid     = blockIdx.x;
    const int logical = (bid & 7) * 64 + (bid >> 3);
    const int half = logical & 1;           // channel half — SCALAR (SGPR)
    const int pb   = logical >> 1;          // pair-block (256 pixel-pairs)

    const int P2  = pb * 256 + threadIdx.x; // pixel-pair id, 0..65535
    const int b   = P2 >> 13;               // 8192 pairs per image
    const int hw0 = (P2 & 8191) << 1;       // even pixel index
    const int h   = hw0 >> 7;
    const int w0  = hw0 & 127;              // even, 0..126

    const size_t imgoff = (size_t)b * 64 * HW;
    const float* xb  = x + imgoff + hw0;
    const float* Wh  = ws + 72 + half * 2304;  // [c][36], scalar base
    const float* bbh = ws + half * 36;         // 36 bias floats for 4 groups

    // ---- phase A: dynamic loop over 8 clusters of 8 channels ----
    // kg[gi*9 + t*3 + d] : group gi (0..3), tap (t,d); .x = px0, .y = px1
    float2 kg[36];
#pragma unroll
    for (int j = 0; j < 36; ++j) { const float t = bbh[j]; kg[j] = make_float2(t, t); }

#pragma unroll 1
    for (int c0 = 0; c0 < 64; c0 += 8) {
        float2 xv[8];
#pragma unroll
        for (int i = 0; i < 8; ++i)
            xv[i] = *reinterpret_cast<const float2*>(xb + (size_t)(c0 + i) * HW);
#pragma unroll
        for (int i = 0; i < 8; ++i) {
#pragma unroll
            for (int j = 0; j < 36; ++j) {
                const float wv = Wh[(c0 + i) * 36 + j];
                kg[j].x = fmaf(wv, xv[i].x, kg[j].x);
                kg[j].y = fmaf(wv, xv[i].y, kg[j].y);
            }
        }
    }

    // ---- phase B prep: row-clamped offsets, masks folded into taps ----
    int rof[3];
#pragma unroll
    for (int t = 0; t < 3; ++t) {
        const int hh = h + t - 1;
        const int hc = hh < 0 ? 0 : (hh > 127 ? 127 : hh);
        rof[t] = (hc - h) * WPX;
        const float m = ((unsigned)hh < 128u) ? 1.f : 0.f;
#pragma unroll
        for (int gi = 0; gi < 4; ++gi)
#pragma unroll
            for (int d = 0; d < 3; ++d) {
                kg[gi * 9 + t * 3 + d].x *= m;
                kg[gi * 9 + t * 3 + d].y *= m;
            }
    }
    // column edges: px0 (w=w0) loses left taps only at w0==0; px1 (w=w0+1)
    // loses right taps only at w0==126. Edge loads are clamped in-bounds;
    // the clamped (finite) value is multiplied by a zeroed tap.
    const int dwl = (w0 == 0)   ? 0 : -1;   // left edge load col (clamped)
    const int dwr = (w0 == 126) ? 1 : 2;    // right edge load col (clamped)
    if (w0 == 0) {
#pragma unroll
        for (int gi = 0; gi < 4; ++gi) {
            kg[gi * 9 + 0].x = 0.f; kg[gi * 9 + 3].x = 0.f; kg[gi * 9 + 6].x = 0.f;
        }
    }
    if (w0 == 126) {
#pragma unroll
        for (int gi = 0; gi < 4; ++gi) {
            kg[gi * 9 + 2].y = 0.f; kg[gi * 9 + 5].y = 0.f; kg[gi * 9 + 8].y = 0.f;
        }
    }

    // ---- phase B: 32 channels; 3x{float2 + 2 scalar} loads, 18 FMA, f2 store ----
#pragma unroll
    for (int ci = 0; ci < 32; ++ci) {
        const int c = half * 32 + ci;
        const float* xc = xb + (size_t)c * HW;
        float2 vC[3];
        float  vL[3], vR[3];
#pragma unroll
        for (int t = 0; t < 3; ++t) {
            vC[t] = *reinterpret_cast<const float2*>(xc + rof[t]); // cols w0,w0+1
            vL[t] = xc[rof[t] + dwl];                              // col w0-1 (clamped)
            vR[t] = xc[rof[t] + dwr];                              // col w0+2 (clamped)
        }
        const int gb = (ci >> 3) * 9;   // group base — static per unrolled iter
        float acc0 = 0.f, acc1 = 0.f;
#pragma unroll
        for (int t = 0; t < 3; ++t) {
            acc0 = fmaf(kg[gb + t * 3 + 0].x, vL[t],   acc0);
            acc0 = fmaf(kg[gb + t * 3 + 1].x, vC[t].x, acc0);
            acc0 = fmaf(kg[gb + t * 3 + 2].x, vC[t].y, acc0);
            acc1 = fmaf(kg[gb + t * 3 + 0].y, vC[t].x, acc1);
            acc1 = fmaf(kg[gb + t * 3 + 1].y, vC[t].y, acc1);
            acc1 = fmaf(kg[gb + t * 3 + 2].y, vR[t],   acc1);
        }
        *reinterpret_cast<float2*>(out + imgoff + (size_t)c * HW + hw0) =
            make_float2(acc0, acc1);
    }
}

// fallback (round-1 kernel) if ws is too small for the weight scratch
__global__ __launch_bounds__(256) void invol_fused_fallback(
    const float* __restrict__ x,
    const float* __restrict__ w_reduce,
    const float* __restrict__ b_reduce,
    const float* __restrict__ w_span,
    const float* __restrict__ b_span,
    float* __restrict__ out)
{
    const int pid = blockIdx.x * 256 + threadIdx.x;
    const int b  = pid >> 14;
    const int hw = pid & 16383;
    const int h  = hw >> 7;
    const int w  = hw & 127;
    const float* xb   = x   + (size_t)b * 64 * HW + hw;
    float*       outb = out + (size_t)b * 64 * HW + hw;
    float y[32];
#pragma unroll
    for (int o = 0; o < 32; ++o) y[o] = b_reduce[o];
#pragma unroll 4
    for (int c = 0; c < 64; ++c) {
        const float xc = xb[(size_t)c * HW];
#pragma unroll
        for (int o = 0; o < 32; ++o)
            y[o] = fmaf(w_reduce[o * 64 + c], xc, y[o]);
    }
    for (int g = 0; g < 8; ++g) {
        float kg[9];
#pragma unroll
        for (int k = 0; k < 9; ++k) {
            float s = b_span[g * 9 + k];
#pragma unroll
            for (int i = 0; i < 32; ++i)
                s = fmaf(w_span[(g * 9 + k) * 32 + i], y[i], s);
            kg[k] = s;
        }
#pragma unroll
        for (int ci = 0; ci < 8; ++ci) {
            const int c = g * 8 + ci;
            const float* xc = xb + (size_t)c * HW;
            float acc = 0.f;
#pragma unroll
            for (int k = 0; k < 9; ++k) {
                const int dh = k / 3 - 1, dw = k % 3 - 1;
                const int hh = h + dh, ww = w + dw;
                float v = ((unsigned)hh < 128u && (unsigned)ww < 128u)
                          ? xc[dh * WPX + dw] : 0.f;
                acc = fmaf(kg[k], v, acc);
            }
            outb[(size_t)c * HW] = acc;
        }
    }
}

extern "C" void kernel_launch(void* const* d_in, const int* in_sizes, int n_in,
                              void* d_out, int out_size, void* d_ws, size_t ws_size,
                              hipStream_t stream) {
    const float* x        = (const float*)d_in[0];
    const float* w_reduce = (const float*)d_in[1];
    const float* b_reduce = (const float*)d_in[2];
    const float* w_span   = (const float*)d_in[3];
    const float* b_span   = (const float*)d_in[4];
    float* out = (float*)d_out;

    const size_t ws_needed = (size_t)(72 + 2 * 64 * 36) * sizeof(float);  // 18720 B
    if (ws_size >= ws_needed) {
        float* ws = (float*)d_ws;
        invol_setup<<<18, 256, 0, stream>>>(w_reduce, b_reduce, w_span, b_span, ws);
        const int npairs = 8 * 128 * 128 / 2;          // 65536
        invol_main<<<npairs / 256 * 2, 256, 0, stream>>>(x, ws, out);  // 512 blocks
    } else {
        const int npix = 8 * 128 * 128;
        invol_fused_fallback<<<npix / 256, 256, 0, stream>>>(
            x, w_reduce, b_reduce, w_span, b_span, out);
    }
}